// Round 8
// baseline (179.825 us; speedup 1.0000x reference)
//
#include <hip/hip_runtime.h>

#define BB 8
#define NN 1024
#define DM 256
#define HH 8
#define HD 32
#define TC 768   // 3*DM

typedef __bf16 bf16x8 __attribute__((ext_vector_type(8)));
typedef __bf16 bf16x4 __attribute__((ext_vector_type(4)));
typedef float  f32x4  __attribute__((ext_vector_type(4)));
typedef unsigned int u32;

// ---------------- precast: x -> bf16, W -> W^T bf16 ----------------
__global__ __launch_bounds__(256) void precast(
    const float* __restrict__ x, const float* __restrict__ W,
    __bf16* __restrict__ xb, __bf16* __restrict__ Wt)
{
  const int tid = threadIdx.x;
  const int bid = blockIdx.x;
  if (bid < 48) {
    __shared__ __bf16 T[64][65];
    const int ct = bid % 12, kt = bid / 12;
    const int c0 = ct * 64, k0 = kt * 64;
    #pragma unroll
    for (int i = 0; i < 16; ++i) {         // read coalesced along c
      int e = tid + i * 256, kk = e >> 6, cc = e & 63;
      T[cc][kk] = (__bf16)W[(size_t)(k0 + kk) * TC + c0 + cc];
    }
    __syncthreads();
    #pragma unroll
    for (int i = 0; i < 16; ++i) {         // write coalesced along k
      int e = tid + i * 256, cc = e >> 6, kk = e & 63;
      Wt[(size_t)(c0 + cc) * DM + k0 + kk] = T[cc][kk];
    }
  } else {
    const size_t e = (size_t)(bid - 48) * 256 + tid;   // float4 index
    const float4 v = ((const float4*)x)[e];
    bf16x4 o;
    o[0] = (__bf16)v.x; o[1] = (__bf16)v.y;
    o[2] = (__bf16)v.z; o[3] = (__bf16)v.w;
    ((bf16x4*)xb)[e] = o;
  }
}

// ---------------- QKV projection: global_load_lds + BK=64 ------------------
__global__ __launch_bounds__(256, 3) void qkv_gemm(
    const __bf16* __restrict__ xb, const __bf16* __restrict__ Wt,
    const float* __restrict__ bias, __bf16* __restrict__ Qb,
    __bf16* __restrict__ Kb, __bf16* __restrict__ Vt)
{
  __shared__ __align__(16) char LDSU[49152];
  __bf16* As0 = (__bf16*)LDSU;             // 16 KB
  __bf16* Bs0 = (__bf16*)(LDSU + 16384);   //  8 KB
  __bf16* As1 = (__bf16*)(LDSU + 24576);   // 16 KB
  __bf16* Bs1 = (__bf16*)(LDSU + 40960);   //  8 KB

  const int tid  = threadIdx.x;
  const int w    = tid >> 6, lane = tid & 63;
  const int n16  = lane & 15, quad = lane >> 4;
  const int m0   = blockIdx.y * 128, c0 = blockIdx.x * 64;
  const int bb   = m0 >> 10, n0 = m0 & 1023;

  const int stRow = w*8 + (lane >> 3);
  const int stG   = (lane & 7) ^ (lane >> 3);
  const __bf16* gA = &xb[(size_t)(m0 + stRow)*DM + stG*8];
  const __bf16* gB = &Wt[(size_t)(c0 + stRow)*DM + stG*8];

#define QKV_STAGE(Adst, Bdst, K0) do {                                        \
    _Pragma("unroll")                                                         \
    for (int i_ = 0; i_ < 4; ++i_) {                                          \
      const __bf16* gp_ = gA + (size_t)(i_*32)*DM + (K0);                     \
      __bf16* lp_ = (Adst) + (i_*32 + w*8)*64;                                \
      __builtin_amdgcn_global_load_lds(                                       \
          (const __attribute__((address_space(1))) u32*)gp_,                  \
          (__attribute__((address_space(3))) u32*)lp_, 16, 0, 0);             \
    }                                                                         \
    _Pragma("unroll")                                                         \
    for (int i_ = 0; i_ < 2; ++i_) {                                          \
      const __bf16* gp_ = gB + (size_t)(i_*32)*DM + (K0);                     \
      __bf16* lp_ = (Bdst) + (i_*32 + w*8)*64;                                \
      __builtin_amdgcn_global_load_lds(                                       \
          (const __attribute__((address_space(1))) u32*)gp_,                  \
          (__attribute__((address_space(3))) u32*)lp_, 16, 0, 0);             \
    }                                                                         \
  } while (0)

  f32x4 acc[2][4] = {};

  QKV_STAGE(As0, Bs0, 0);
  __syncthreads();

  #pragma unroll
  for (int kk = 0; kk < 4; ++kk) {
    __bf16* Ac = (kk & 1) ? As1 : As0;
    __bf16* Bc = (kk & 1) ? Bs1 : Bs0;
    if (kk == 0)      QKV_STAGE(As1, Bs1, 64);
    else if (kk == 1) QKV_STAGE(As0, Bs0, 128);
    else if (kk == 2) QKV_STAGE(As1, Bs1, 192);
    #pragma unroll
    for (int ks = 0; ks < 2; ++ks) {
      const int ch = ((ks*4 + quad) ^ (n16 & 7)) * 8;   // bf16 offset in row
      bf16x8 af0 = *(const bf16x8*)&Ac[(w*32 + n16)*64 + ch];
      bf16x8 af1 = *(const bf16x8*)&Ac[(w*32 + 16 + n16)*64 + ch];
      #pragma unroll
      for (int cb = 0; cb < 4; ++cb) {
        bf16x8 bfb = *(const bf16x8*)&Bc[(cb*16 + n16)*64 + ch];
        acc[0][cb] = __builtin_amdgcn_mfma_f32_16x16x32_bf16(af0, bfb, acc[0][cb], 0, 0, 0);
        acc[1][cb] = __builtin_amdgcn_mfma_f32_16x16x32_bf16(af1, bfb, acc[1][cb], 0, 0, 0);
      }
    }
    __syncthreads();
  }

  float bv[4];
  #pragma unroll
  for (int cb = 0; cb < 4; ++cb) bv[cb] = bias[c0 + cb*16 + n16];

  if (c0 < 512) {
    __bf16* Ct = (__bf16*)LDSU;
    #pragma unroll
    for (int cb = 0; cb < 4; ++cb)
      #pragma unroll
      for (int mb = 0; mb < 2; ++mb)
        #pragma unroll
        for (int r = 0; r < 4; ++r)
          Ct[(w*32 + mb*16 + quad*4 + r)*72 + cb*16 + n16] =
              (__bf16)(acc[mb][cb][r] + bv[cb]);
    __syncthreads();
    const int chunk = tid & 3, hh = (tid >> 2) & 1, rbase = tid >> 3;
    const int c_head = c0 + hh*32;
    const int h = (c_head >> 5) & 7;
    __bf16* base = (c_head >> 8) ? Kb : Qb;
    #pragma unroll
    for (int it = 0; it < 4; ++it) {
      int rl = rbase + it*32;
      bf16x8 v = *(const bf16x8*)&Ct[rl*72 + hh*32 + chunk*8];
      *(bf16x8*)&base[((size_t)((bb*HH + h)*NN + n0 + rl))*HD + chunk*8] = v;
    }
  } else {
    __bf16* CtT = (__bf16*)LDSU;
    #pragma unroll
    for (int cb = 0; cb < 4; ++cb)
      #pragma unroll
      for (int mb = 0; mb < 2; ++mb) {
        bf16x4 t;
        #pragma unroll
        for (int r = 0; r < 4; ++r) t[r] = (__bf16)(acc[mb][cb][r] + bv[cb]);
        *(bf16x4*)&CtT[(cb*16 + n16)*136 + w*32 + mb*16 + quad*4] = t;
      }
    __syncthreads();
    const int col = tid >> 2, sg = tid & 3;
    const int c = c0 + col;
    const int h = (c >> 5) & 7, dd = c & 31;
    __bf16* dst = &Vt[((size_t)((bb*HH + h)*HD + dd))*NN + n0 + sg*32];
    const __bf16* srcp = &CtT[col*136 + sg*32];
    #pragma unroll
    for (int q2 = 0; q2 < 4; ++q2)
      *(bf16x8*)&dst[q2*8] = *(const bf16x8*)&srcp[q2*8];
  }
}

// ---------------- fused moire attention (R17: barrier-free) ----------------
// block = (bh, 32-q tile); 4 waves = 2 q-groups x 2 j-halves; grid 2048.
// NO K/V LDS staging: K/V per head = 64KB each, L2-resident; both fragment
// layouts load DIRECTLY from global with perfect coalescing (16 rows x 64B
// dense per instruction):
//   kf(cb) = K[j0+jh*32+cb*16+n16][quad*8..]          (K row-major, 64B rows)
//   b0/b1  = Vt[n16 / 16+n16][j0+jh*32+quad*8..]      (V pre-transposed)
// Ps is WAVE-PRIVATE [16][40] (80B stride: b16 writes land 2 lanes/bank =
// free per m136); same-wave ds ordering needs no barrier. ZERO __syncthreads
// in the main loop — waves free-run, latency hidden by 32 waves/CU TLP
// (launch_bounds(256,8) caps VGPR at 64 for 8 waves/SIMD; LDS 11.3KB).
// One barrier pair at the end merges j-half partials (o0,o1,lacc).
__global__ __launch_bounds__(256, 8) void attn_kernel(
    const __bf16* __restrict__ Q, const __bf16* __restrict__ K,
    const __bf16* __restrict__ Vt, const float* __restrict__ adj,
    const int* __restrict__ mask, const float* __restrict__ shifts,
    const float* __restrict__ widths, const float* __restrict__ slw,
    float* __restrict__ out)
{
  __shared__ __align__(16) __bf16 Ps[4][16][40];   // 5 KB, per-wave private
  __shared__ __align__(16) float  Red[2][64][12];  // 6 KB, j-half merge

  const int tid  = threadIdx.x;
  const int w    = tid >> 6, lane = tid & 63;
  const int n16  = lane & 15, quad = lane >> 4;
  const int qg   = w >> 1, jh = w & 1;
  const int bh   = blockIdx.x >> 5, qt = blockIdx.x & 31;
  const int b    = bh >> 3, h = bh & 7;
  const int q0   = qt * 32;

  const float L2E   = 1.4426950408889634f;
  const float sh    = shifts[h];
  const float ninvw = -L2E / fmaxf(widths[h], 0.5f);
  const float slv   = slw[h] * L2E;
  const float scl   = 0.17677669529663687f * L2E;
  const float MASKV = -28.0f;
  const float c1 = -2.0f * sh * ninvw;
  const float c2 = sh * sh * ninvw;

  const __bf16* Kg = K + (size_t)bh*NN*HD;
  const __bf16* Vg = Vt + (size_t)bh*HD*NN;

  // per-lane fragment base pointers (direct global)
  const __bf16* kfp  = Kg + (size_t)(jh*32 + n16)*HD + quad*8;
  const __bf16* vfp0 = Vg + (size_t)n16*NN + jh*32 + quad*8;
  const __bf16* vfp1 = vfp0 + (size_t)16*NN;

  // q-side invariants
  const bf16x8 qf =
      *(const bf16x8*)&Q[((size_t)bh*NN + q0 + qg*16 + n16)*HD + quad*8];
  int mq[4];
  #pragma unroll
  for (int r = 0; r < 4; ++r) mq[r] = mask[b*NN + q0 + qg*16 + quad*4 + r];

  // adj row pointers (4 q-rows per lane-quad; dense 64B per row per instr)
  const float* ar0 = adj + ((size_t)(b*NN + q0 + qg*16 + quad*4))*NN + jh*32 + n16;
  const float* ar1 = ar0 + NN;
  const float* ar2 = ar0 + 2*NN;
  const float* ar3 = ar0 + 3*NN;
  const int*   mrp = mask + b*NN + jh*32 + n16;

  const f32x4 zero = {0.f, 0.f, 0.f, 0.f};
  f32x4 o0 = zero, o1 = zero, lacc = zero;
  bf16x8 onesb;
  #pragma unroll
  for (int i = 0; i < 8; ++i) onesb[i] = (__bf16)1.0f;

  const bool mydiagH = (jh == (qt & 1));   // diag falls in this wave's j-half
  const int  dT  = qt >> 1;                // j-tile containing the diagonal
  const int  dlr = n16 - quad*4;           // diag hits reg r == dlr (if 0..3)

  __bf16 (*myPs)[40] = Ps[w];

  #pragma unroll 2
  for (int jtl = 0; jtl < 16; ++jtl) {
    const int j0 = jtl * 64;

    // K/V fragments straight from global (L1/L2-hot, coalesced 16Bx64)
    bf16x8 kf0 = *(const bf16x8*)&kfp[(size_t)j0*HD];
    bf16x8 kf1 = *(const bf16x8*)&kfp[(size_t)(j0 + 16)*HD];
    bf16x8 b0  = *(const bf16x8*)&vfp0[j0];
    bf16x8 b1  = *(const bf16x8*)&vfp1[j0];

    // adj + mask for this tile (issued early, consumed after QK MFMAs)
    int mj[2];
    mj[0] = mrp[j0]; mj[1] = mrp[j0 + 16];
    float av[4][2];
    #pragma unroll
    for (int cb = 0; cb < 2; ++cb) {
      av[0][cb] = ar0[j0 + cb*16];
      av[1][cb] = ar1[j0 + cb*16];
      av[2][cb] = ar2[j0 + cb*16];
      av[3][cb] = ar3[j0 + cb*16];
    }

    f32x4 s0 = __builtin_amdgcn_mfma_f32_16x16x32_bf16(qf, kf0, zero, 0, 0, 0);
    f32x4 s1 = __builtin_amdgcn_mfma_f32_16x16x32_bf16(qf, kf1, zero, 0, 0, 0);

    const bool diagt = mydiagH && (jtl == dT);
    #pragma unroll
    for (int r = 0; r < 4; ++r) {
      #pragma unroll
      for (int cb = 0; cb < 2; ++cb) {
        float a   = av[r][cb];
        float mo  = fmaf(a, fmaf(a, ninvw, c1), c2);   // 2-FMA moire
        float val = fmaf((cb ? s1[r] : s0[r]), scl, mo);
        if (diagt && (cb == qg) && (dlr == r)) val += slv;
        bool ok = (mq[r] != 0) && (mj[cb] != 0);
        val = ok ? val : MASKV;
        myPs[quad*4 + r][cb*16 + n16] = (__bf16)__builtin_amdgcn_exp2f(val);
      }
    }

    bf16x8 a0 = *(const bf16x8*)&myPs[n16][quad*8];
    o0   = __builtin_amdgcn_mfma_f32_16x16x32_bf16(a0, b0, o0, 0, 0, 0);
    o1   = __builtin_amdgcn_mfma_f32_16x16x32_bf16(a0, b1, o1, 0, 0, 0);
    lacc = __builtin_amdgcn_mfma_f32_16x16x32_bf16(a0, onesb, lacc, 0, 0, 0);
  }

  // merge j-half partials (single barrier pair in the whole kernel)
  if (jh) {
    float* p = &Red[qg][lane][0];
    *(f32x4*)&p[0] = o0; *(f32x4*)&p[4] = o1; *(f32x4*)&p[8] = lacc;
  }
  __syncthreads();
  if (!jh) {
    const float* p = &Red[qg][lane][0];
    o0   += *(const f32x4*)&p[0];
    o1   += *(const f32x4*)&p[4];
    lacc += *(const f32x4*)&p[8];
    #pragma unroll
    for (int r = 0; r < 4; ++r) {
      const float invl = 1.0f / lacc[r];
      const int n = q0 + qg*16 + quad*4 + r;
      float* og = out + ((size_t)(b*NN + n))*DM + h*HD;
      og[n16]      = o0[r] * invl;
      og[16 + n16] = o1[r] * invl;
    }
  }
}

extern "C" void kernel_launch(void* const* d_in, const int* in_sizes, int n_in,
                              void* d_out, int out_size, void* d_ws, size_t ws_size,
                              hipStream_t stream) {
  const float* x      = (const float*)d_in[0];
  const float* adj    = (const float*)d_in[1];
  const int*   mask   = (const int*)d_in[2];
  const float* W      = (const float*)d_in[3];
  const float* bias   = (const float*)d_in[4];
  const float* shifts = (const float*)d_in[5];
  const float* widths = (const float*)d_in[6];
  const float* slwp   = (const float*)d_in[7];
  float* out = (float*)d_out;

  const size_t BHND = (size_t)BB*HH*NN*HD;          // 2,097,152
  const size_t WTN  = (size_t)TC*DM;                // 196,608
  __bf16* xbuf = (__bf16*)d_ws;                      // [8192,256] bf16
  __bf16* Wt   = xbuf + BHND;                        // [768,256] bf16
  __bf16* Qb   = Wt + WTN;                           // [B,H,N,32]
  __bf16* Kb   = Qb + BHND;
  __bf16* Vt   = Kb + BHND;

  precast<<<dim3(48 + (int)(BHND/4/256)), 256, 0, stream>>>(x, W, xbuf, Wt);
  qkv_gemm<<<dim3(TC/64, (BB*NN)/128), 256, 0, stream>>>(xbuf, Wt, bias, Qb, Kb, Vt);
  attn_kernel<<<dim3(BB*HH*32), 256, 0, stream>>>(Qb, Kb, Vt, adj, mask,
                                                  shifts, widths, slwp, out);
}